// Round 16
// baseline (229.018 us; speedup 1.0000x reference)
//
#include <hip/hip_runtime.h>
#include <hip/hip_bf16.h>
#include <stdint.h>

#define GN   6000
#define GNP2 3000          // row pairs
#define GFIN 512
#define GNH  8
#define GNC  40
#define WPR  192           // bitmask words per row (192*32 = 6144)
#define NT   192           // j-tiles per head (tail tiles zero-padded)
#define NRT  375           // row-tiles (16 rows), 375*16 = 6000 exact
#define PQS  6144
#define PQH  (PQS/2)       // pair-dwords per head
#define KC1  8             // attn1 K-chunks (24 w each)
#define CW1  24
#define KC2  32            // attn2 K-chunks (6 w each)
#define CW2  6

typedef __attribute__((ext_vector_type(8))) _Float16 half8v;  // 8 f16 (4 VGPRs)
typedef __attribute__((ext_vector_type(2))) _Float16 half2v;
typedef __attribute__((ext_vector_type(4))) float float4v;    // MFMA acc
typedef __attribute__((ext_vector_type(4))) float f32x4;

__device__ __forceinline__ uint32_t packh(float a, float b){
  half2v h = { (_Float16)a, (_Float16)b };
  return *(uint32_t*)&h;
}
__device__ __forceinline__ float h2lo(uint32_t u){ half2v h = *(half2v*)&u; return (float)h.x; }
__device__ __forceinline__ float h2hi(uint32_t u){ half2v h = *(half2v*)&u; return (float)h.y; }
// k-pair base for fragment dword t within k-group g (16x16x32 layout)
__device__ __forceinline__ int kmap(int g, int t){
  return (t < 2) ? 4*g + 2*t : 16 + 4*g + 2*(t - 2);
}
// permuted bit position: lane-group g's 8 bits contiguous at byte g
__device__ __forceinline__ int newpos(int gg, int c){
  return (gg < 4) ? 8*gg + c : 8*(gg-4) + 4 + c;
}
// masked weight: wv = m & max(p, ti*q), all packed f16 pairs
__device__ __forceinline__ uint32_t wvbuild(uint32_t ti2, uint32_t pq_q, uint32_t pq_p, uint32_t m){
  uint32_t prod, wvu;
  asm("v_pk_mul_f16 %0, %1, %2" : "=v"(prod) : "v"(ti2), "v"(pq_q));
  asm("v_pk_max_f16 %0, %1, %2" : "=v"(wvu) : "v"(pq_p), "v"(prod));
  return wvu & m;
}
// mask pair for bits (2t,2t+1) from u = b8 | (b8<<15): 2 ops per dword.
// (b8<<(15-2t))|(b8<<(30-2t)) == u<<(15-2t); pk_ashr by 15 keeps only each
// half's bit-15 sign -> 0xFFFF/0x0000 per half; stray bits shift out.
__device__ __forceinline__ uint32_t mbuild_u(uint32_t u, int t, uint32_t s15){
  uint32_t pre = u << (15 - 2*t);
  uint32_t m;
  asm("v_pk_ashrrev_i16 %0, %1, %2" : "=v"(m) : "v"(s15), "v"(pre));
  return m;
}

// ---- prep: pad a2; zero pq arrays; zero Wt pad tiles (187..191) ----
__global__ void k_prep(const float* __restrict__ as2, const float* __restrict__ at2,
                       float* __restrict__ as2f, float* __restrict__ at2f,
                       uint32_t* __restrict__ Wt1, uint32_t* __restrict__ Wt2,
                       uint32_t* __restrict__ pqk1, uint32_t* __restrict__ pqk2){
  int i = blockIdx.x * 256 + threadIdx.x;
  if (i < 64) { as2f[i] = (i < GNC) ? as2[i] : 0.f; at2f[i] = (i < GNC) ? at2[i] : 0.f; }
  if (i < GNH*PQH*2) pqk1[i] = 0u;
  if (i < PQH*2) pqk2[i] = 0u;
  if (i < GNH*5*1024) {
    int h = i / 5120, rem = i - h * 5120;
    Wt1[((size_t)h*NT + 187)*1024 + rem] = 0u;
  }
  if (i < 5*1024) Wt2[(size_t)187*1024 + i] = 0u;
}

// ---- adjacency -> byte-permuted bitmask ----
__global__ void k_bitmask(const int* __restrict__ adj, uint32_t* __restrict__ bm){
  int idx = blockIdx.x * 256 + threadIdx.x;
  if (idx >= GN * WPR) return;
  int row = idx / WPR, w = idx - row * WPR;
  int j0 = w * 32;
  uint32_t bits = 0u;
  if (j0 < GN) {
    const int* a = adj + (size_t)row * GN + j0;
    int lim = GN - j0;
    if (lim >= 32) {
      const int4* a4 = (const int4*)a;
      #pragma unroll
      for (int gg = 0; gg < 8; ++gg) {
        int4 v = a4[gg];
        bits |= (v.x != 0 ? 1u : 0u) << newpos(gg, 0);
        bits |= (v.y != 0 ? 1u : 0u) << newpos(gg, 1);
        bits |= (v.z != 0 ? 1u : 0u) << newpos(gg, 2);
        bits |= (v.w != 0 ? 1u : 0u) << newpos(gg, 3);
      }
    } else {
      for (int b = 0; b < lim; ++b)
        bits |= (a[b] != 0 ? 1u : 0u) << newpos(b >> 2, b & 3);
    }
  }
  bm[idx] = bits;
}

// ---- x (f32) -> A-tiled f16 ----
__global__ void k_xtile(const float* __restrict__ x, uint32_t* __restrict__ xt){
  int idx = blockIdx.x * 256 + threadIdx.x;      // 375*16*256 exact
  int e = idx & 3, lane = (idx >> 2) & 63, kt = (idx >> 8) & 15, rt = idx >> 12;
  int g = lane >> 4, r = lane & 15;
  int k0 = kt*32 + kmap(g, e);
  const float* xp = x + (size_t)(rt*16 + r) * GFIN + k0;
  xt[idx] = packh(xp[0], xp[1]);
}

// ---- W1 -> B-tiled f16 ----
__global__ void k_wtile1(const float* __restrict__ W1, uint32_t* __restrict__ Wb1){
  int idx = blockIdx.x * 256 + threadIdx.x;      // 131072 exact
  int e = idx & 3, lane = (idx >> 2) & 63, n = (idx >> 8) & 3, kt = (idx >> 10) & 15, h = idx >> 14;
  int g = lane >> 4, col = n*16 + (lane & 15);
  int k0 = kt*32 + kmap(g, e);
  const float* wp = W1 + ((size_t)h*GFIN + k0) * 64 + col;
  Wb1[idx] = packh(wp[0], wp[64]);
}

// ---- W2 -> B-tiled f16, cols padded to 64 ----
__global__ void k_wtile2(const float* __restrict__ W2, uint32_t* __restrict__ Wb2){
  int idx = blockIdx.x * 256 + threadIdx.x;      // 16384 exact
  int e = idx & 3, lane = (idx >> 2) & 63, n = (idx >> 8) & 3, kt = idx >> 10;
  int g = lane >> 4, col = n*16 + (lane & 15);
  int k0 = kt*32 + kmap(g, e);
  float v0 = (col < GNC) ? W2[(size_t)k0*GNC + col]     : 0.f;
  float v1 = (col < GNC) ? W2[(size_t)(k0+1)*GNC + col] : 0.f;
  Wb2[idx] = packh(v0, v1);
}

// ---- MFMA GEMM (f16) -> Wh tiled f16 (optional ones-column) + scores ----
__global__ __launch_bounds__(256) void k_gemm_mfma(
    const uint32_t* __restrict__ At, const uint32_t* __restrict__ Bt,
    const float* __restrict__ asv, const float* __restrict__ atv,
    uint32_t* __restrict__ Wt, float* __restrict__ ss, float* __restrict__ st,
    int ones_col){
  int lane = threadIdx.x & 63;
  int wid  = threadIdx.x >> 6;
  int h  = blockIdx.y;
  int rt = blockIdx.x * 4 + wid;
  if (rt >= NRT) return;
  int g = lane >> 4, r = lane & 15;
  const uint32_t* Ab = At + (size_t)rt * 16 * 256 + lane * 4;
  const uint32_t* Bb = Bt + (size_t)h * 16 * 1024 + lane * 4;
  float4v acc[4];
  #pragma unroll
  for (int n = 0; n < 4; ++n) acc[n] = (float4v){0,0,0,0};
  for (int kt = 0; kt < 16; ++kt) {
    union { uint4 v; half8v hv; } A;
    A.v = *(const uint4*)(Ab + kt*256);
    #pragma unroll
    for (int n = 0; n < 4; ++n) {
      union { uint4 v; half8v hv; } B;
      B.v = *(const uint4*)(Bb + kt*1024 + n*256);
      acc[n] = __builtin_amdgcn_mfma_f32_16x16x32_f16(A.hv, B.hv, acc[n], 0, 0, 0);
    }
  }
  int row0 = rt * 16;
  int t01  = (row0 & 16) ? 2 : 0;
  uint32_t* dst = Wt + ((size_t)h*NT + (row0 >> 5)) * 1024 + lane*4 + t01;
  #pragma unroll
  for (int n = 0; n < 4; ++n) {
    uint2 val;
    if (n*16 + r == ones_col) val = make_uint2(0x3C003C00u, 0x3C003C00u);
    else val = make_uint2(packh(acc[n][0], acc[n][1]), packh(acc[n][2], acc[n][3]));
    *(uint2*)(dst + n*256) = val;
  }
  float av[4], tv[4];
  #pragma unroll
  for (int n = 0; n < 4; ++n) { av[n] = asv[h*64 + n*16 + r]; tv[n] = atv[h*64 + n*16 + r]; }
  #pragma unroll
  for (int reg = 0; reg < 4; ++reg) {
    float a = 0.f, b = 0.f;
    #pragma unroll
    for (int n = 0; n < 4; ++n) { a = fmaf(av[n], acc[n][reg], a); b = fmaf(tv[n], acc[n][reg], b); }
    #pragma unroll
    for (int d = 1; d < 16; d <<= 1) { a += __shfl_xor(a, d, 64); b += __shfl_xor(b, d, 64); }
    if (r == 0) {
      ss[(size_t)h*GN + row0 + 4*g + reg] = a;
      st[(size_t)h*GN + row0 + 4*g + reg] = b;
    }
  }
}

// ---- column stats: mh = max(s); interleaved pq pairs [p01,q01] per jp ----
__global__ void k_stats(const float* __restrict__ s_tgt, float* __restrict__ mh_out,
                        uint32_t* __restrict__ pqk){
  int h = blockIdx.x;
  __shared__ float red[256];
  float mx = -3.0e38f;
  for (int n = threadIdx.x; n < GN; n += 256) mx = fmaxf(mx, s_tgt[(size_t)h*GN + n]);
  red[threadIdx.x] = mx;
  __syncthreads();
  for (int d = 128; d > 0; d >>= 1) {
    if (threadIdx.x < d) red[threadIdx.x] = fmaxf(red[threadIdx.x], red[threadIdx.x + d]);
    __syncthreads();
  }
  float mh = red[0];
  if (threadIdx.x == 0) mh_out[h] = mh;
  for (int jp = threadIdx.x; jp < GNP2; jp += 256) {
    float s0 = s_tgt[(size_t)h*GN + 2*jp];
    float s1 = s_tgt[(size_t)h*GN + 2*jp + 1];
    pqk[((size_t)h*PQH + jp)*2]     = packh(expf(s0 - mh), expf(s1 - mh));
    pqk[((size_t)h*PQH + jp)*2 + 1] = packh(expf(0.2f*(s0 - mh)), expf(0.2f*(s1 - mh)));
  }
}

// ---- attention: 64 rows/wave, shared-u mask build, setprio'd MFMA cluster ----
template<int CW, int NH, int KC, int NTILES, bool ONES>
__global__ __launch_bounds__(256) void k_attn_t(
    const uint32_t* __restrict__ bmp, const uint32_t* __restrict__ Wt,
    const float* __restrict__ ss, const float* __restrict__ mh_arr,
    const uint32_t* __restrict__ pqk,
    uint32_t* __restrict__ part, float* __restrict__ Zp){
  int lane = threadIdx.x & 63;
  int wid  = threadIdx.x >> 6;
  constexpr int NB = NH * KC;        // NB % 8 == 0 -> (h,ch) pinned to one XCD
  int combo = blockIdx.x % NB;
  int x     = blockIdx.x / NB;
  int h  = combo / KC;
  int ch = combo % KC;
  int base = x * 256 + wid * 64;
  int g = lane >> 4, r = lane & 15;
  uint32_t s15 = 0x000F000Fu;
  float mh = mh_arr[h];
  const uint32_t* bmr[4];
  uint32_t ti2u[4];
  #pragma unroll
  for (int tt = 0; tt < 4; ++tt) {
    int row = base + 16*tt + r;
    int rc = row < GN-1 ? row : GN-1;
    float ti = expf(-0.8f * (ss[(size_t)h*GN + rc] + mh));
    ti2u[tt] = packh(ti, ti);
    bmr[tt] = bmp + (size_t)rc * WPR;
  }
  const uint32_t* pqh = pqk + (size_t)h * PQH * 2;
  const uint32_t* wt  = Wt + (size_t)h * NT * 1024;
  float4v acc[4][NTILES];
  float4v az[4];
  #pragma unroll
  for (int tt = 0; tt < 4; ++tt) {
    #pragma unroll
    for (int n = 0; n < NTILES; ++n) acc[tt][n] = (float4v){0,0,0,0};
    if (ONES) az[tt] = (float4v){0,0,0,0};
  }
  union { uint32_t u4[4]; half8v hv; } Bones;
  if (ONES) {
    uint32_t ov = (r == 0) ? 0x3C003C00u : 0u;
    Bones.u4[0] = ov; Bones.u4[1] = ov; Bones.u4[2] = ov; Bones.u4[3] = ov;
  }
  const int w0 = ch * CW;
  for (int wp = 0; wp < CW/2; ++wp) {
    uint2 bw2[4];
    #pragma unroll
    for (int tt = 0; tt < 4; ++tt) bw2[tt] = *(const uint2*)(bmr[tt] + w0 + 2*wp);
    #pragma unroll
    for (int e = 0; e < 2; ++e) {
      int w = w0 + 2*wp + e;
      int jp = w * 16;
      uint4 pqA = *(const uint4*)(pqh + (size_t)(jp + 2*g) * 2);      // p01 q01 p23 q23
      uint4 pqB = *(const uint4*)(pqh + (size_t)(jp + 8 + 2*g) * 2);
      const uint32_t* tb = wt + (size_t)w * 1024 + lane * 4;
      union { uint4 v; half8v hv; } B[NTILES];
      #pragma unroll
      for (int n = 0; n < NTILES; ++n) B[n].v = *(const uint4*)(tb + n*256);
      #pragma unroll
      for (int tt = 0; tt < 4; ++tt) {
        uint32_t b8 = ((e ? bw2[tt].y : bw2[tt].x) >> (8*g)) & 0xFFu;
        uint32_t u = b8 | (b8 << 15);       // shared mask base (2 ops / 4 dwords)
        union { uint32_t u4[4]; half8v hv; } A;
        A.u4[0] = wvbuild(ti2u[tt], pqA.y, pqA.x, mbuild_u(u, 0, s15));
        A.u4[1] = wvbuild(ti2u[tt], pqA.w, pqA.z, mbuild_u(u, 1, s15));
        A.u4[2] = wvbuild(ti2u[tt], pqB.y, pqB.x, mbuild_u(u, 2, s15));
        A.u4[3] = wvbuild(ti2u[tt], pqB.w, pqB.z, mbuild_u(u, 3, s15));
        __builtin_amdgcn_s_setprio(1);
        #pragma unroll
        for (int n = 0; n < NTILES; ++n)
          acc[tt][n] = __builtin_amdgcn_mfma_f32_16x16x32_f16(A.hv, B[n].hv, acc[tt][n], 0, 0, 0);
        if (ONES)
          az[tt] = __builtin_amdgcn_mfma_f32_16x16x32_f16(A.hv, Bones.hv, az[tt], 0, 0, 0);
        __builtin_amdgcn_s_setprio(0);
      }
    }
  }
  constexpr int PST = NTILES * 16;
  size_t pb = ((size_t)(ch * NH + h)) * GNP2;
  #pragma unroll
  for (int tt = 0; tt < 4; ++tt) {
    int row0t = base + 16*tt;
    if (row0t >= GN) break;                 // tiles are 16-aligned: all-or-nothing
    int pra = (row0t >> 1) + 2*g;
    #pragma unroll
    for (int n = 0; n < NTILES; ++n) {
      part[(pb + pra    )*PST + n*16 + r] = packh(acc[tt][n][0], acc[tt][n][1]);
      part[(pb + pra + 1)*PST + n*16 + r] = packh(acc[tt][n][2], acc[tt][n][3]);
    }
    if (ONES && r == 0) {
      size_t zb = ((size_t)(ch * NH + h)) * GN;
      #pragma unroll
      for (int reg = 0; reg < 4; ++reg) Zp[zb + row0t + 4*g + reg] = az[tt][reg];
    }
  }
}

// ---- combine L1 chunks (f16 pairs): normalize, ELU, h1 A-tile f16 write ----
__global__ void k_reduce1(const uint32_t* __restrict__ part1, const float* __restrict__ Zp1,
                          uint32_t* __restrict__ h1t){
  int idx = blockIdx.x * 256 + threadIdx.x;
  if (idx >= GNH*GNP2*64) return;
  int o = idx & 63;
  int t = idx >> 6;
  int pr = t % GNP2;
  int h = t / GNP2;
  float s0 = 0.f, s1 = 0.f, z0 = 0.f, z1 = 0.f;
  #pragma unroll
  for (int c = 0; c < KC1; ++c) {
    uint32_t dw = part1[(((size_t)(c*GNH + h))*GNP2 + pr)*64 + o];
    s0 += h2lo(dw);
    s1 += h2hi(dw);
    size_t zb = ((size_t)(c*GNH + h))*GN + 2*pr;
    z0 += Zp1[zb]; z1 += Zp1[zb + 1];
  }
  float v0 = s0 / z0, v1 = s1 / z1;
  v0 = v0 > 0.f ? v0 : (expf(v0) - 1.f);
  v1 = v1 > 0.f ? v1 : (expf(v1) - 1.f);
  int n0 = 2*pr;
  int rt = n0 >> 4, rr = n0 & 15;
  int k = h*64 + o;
  int kt = k >> 5, joff = k & 31;
  int g, tt, b;
  if (joff < 16) { g = joff >> 2; tt = (joff & 3) >> 1;        b = joff & 1; }
  else { int jo = joff - 16; g = jo >> 2; tt = 2 + ((jo & 3) >> 1); b = jo & 1; }
  size_t dw0 = ((size_t)(rt*16 + kt))*256 + (g*16 + rr)*4 + tt;
  _Float16* hp = (_Float16*)h1t;
  hp[dw0*2 + b]     = (_Float16)v0;
  hp[(dw0+4)*2 + b] = (_Float16)v1;
}

// ---- combine L2 chunks: normalize (Z = col 47), f32 logits ----
__global__ void k_reduce2(const uint32_t* __restrict__ part2, float* __restrict__ out){
  int idx = blockIdx.x * 256 + threadIdx.x;
  if (idx >= GN * GNC) return;
  int n = idx / GNC, c = idx - n * GNC;
  int pr = n >> 1, half = n & 1;
  float s = 0.f, z = 0.f;
  #pragma unroll 8
  for (int ch = 0; ch < KC2; ++ch) {
    const uint32_t* row = part2 + ((size_t)ch * GNP2 + pr) * 48;
    uint32_t dS = row[c], dZ = row[47];
    s += half ? h2hi(dS) : h2lo(dS);
    z += half ? h2hi(dZ) : h2lo(dZ);
  }
  out[idx] = s / z;
}

// ---- adjacency echo (f32): one float4 per thread, globally contiguous stores ----
__global__ void k_echo(const uint32_t* __restrict__ bm, float* __restrict__ echo){
  int idx = blockIdx.x * 256 + threadIdx.x;     // GN*1500 = 9,000,000 exact chunks
  if (idx >= GN * 1500) return;
  int row = idx / 1500, c = idx - row * 1500;
  uint32_t bits = bm[(size_t)row * WPR + (c >> 3)];
  int gg = c & 7;
  f32x4 f;
  f.x = ((bits >> newpos(gg,0)) & 1u) ? 1.f : 0.f;
  f.y = ((bits >> newpos(gg,1)) & 1u) ? 1.f : 0.f;
  f.z = ((bits >> newpos(gg,2)) & 1u) ? 1.f : 0.f;
  f.w = ((bits >> newpos(gg,3)) & 1u) ? 1.f : 0.f;
  *(f32x4*)(echo + (size_t)idx * 4) = f;
}

extern "C" void kernel_launch(void* const* d_in, const int* in_sizes, int n_in,
                              void* d_out, int out_size, void* d_ws, size_t ws_size,
                              hipStream_t stream){
  const float* x   = (const float*)d_in[0];
  const int*   adj = (const int*)d_in[1];
  const float* W1  = (const float*)d_in[2];
  const float* as1 = (const float*)d_in[3];
  const float* at1 = (const float*)d_in[4];
  const float* W2  = (const float*)d_in[5];
  const float* as2 = (const float*)d_in[6];
  const float* at2 = (const float*)d_in[7];
  float* out  = (float*)d_out;                    // f32 logits [6000,40]
  float* echo = out + (size_t)GN * GNC;           // f32 adj echo [6000,6000]
  (void)in_sizes; (void)n_in; (void)out_size; (void)ws_size;

  // scratch in echo region (dead before k_echo overwrites)
  uint32_t* part1u = (uint32_t*)echo;                              // 12.288M dw
  float*    Zp1    = (float*)(part1u + (size_t)KC1*GNH*GNP2*64);   // 384K f32
  uint32_t* part2u = (uint32_t*)(Zp1 + (size_t)KC1*GNH*GN);        // 4.608M dw
  uint32_t* h1t    = part2u + (size_t)KC2*GNP2*48;                 // 1.536M dw
  uint32_t* xt     = h1t + (size_t)NRT*16*256;                     // 1.536M dw

  char* wsb = (char*)d_ws;
  size_t off = 0;
  auto alloc = [&](size_t bytes) -> void* {
    void* r = wsb + off;
    off = (off + bytes + 255) & ~(size_t)255;
    return r;
  };
  uint32_t* bmp  = (uint32_t*)alloc((size_t)GN * WPR * 4);
  uint32_t* Wt1  = (uint32_t*)alloc((size_t)GNH * NT * 1024 * 4);
  uint32_t* Wt2  = (uint32_t*)alloc((size_t)NT * 1024 * 4);
  uint32_t* Wb1  = (uint32_t*)alloc((size_t)GNH * 16 * 1024 * 4);
  uint32_t* Wb2  = (uint32_t*)alloc((size_t)16 * 1024 * 4);
  float*    as2f = (float*)alloc(64 * 4);
  float*    at2f = (float*)alloc(64 * 4);
  float*    ss1  = (float*)alloc((size_t)GNH * GN * 4);
  float*    st1  = (float*)alloc((size_t)GNH * GN * 4);
  uint32_t* pqk1 = (uint32_t*)alloc((size_t)GNH * PQH * 2 * 4);
  float*    m1   = (float*)alloc(64);
  float*    ss2  = (float*)alloc((size_t)GN * 4);
  float*    st2  = (float*)alloc((size_t)GN * 4);
  uint32_t* pqk2 = (uint32_t*)alloc((size_t)PQH * 2 * 4);
  float*    m2   = (float*)alloc(64);

  const int NX = (GN + 255) / 256;    // 24 row-blocks (attn, 256 rows each)

  hipLaunchKernelGGL(k_prep, dim3(192), dim3(256), 0, stream,
      as2, at2, as2f, at2f, Wt1, Wt2, pqk1, pqk2);
  hipLaunchKernelGGL(k_bitmask, dim3(GN*WPR/256), dim3(256), 0, stream, adj, bmp);
  hipLaunchKernelGGL(k_xtile, dim3(NRT*16*256/256), dim3(256), 0, stream, x, xt);
  hipLaunchKernelGGL(k_wtile1, dim3(512), dim3(256), 0, stream, W1, Wb1);
  hipLaunchKernelGGL(k_wtile2, dim3(64), dim3(256), 0, stream, W2, Wb2);
  hipLaunchKernelGGL(k_gemm_mfma, dim3((NRT+3)/4, GNH), dim3(256), 0, stream,
      xt, Wb1, as1, at1, Wt1, ss1, st1, -1);
  hipLaunchKernelGGL(k_stats, dim3(GNH), dim3(256), 0, stream, st1, m1, pqk1);
  hipLaunchKernelGGL((k_attn_t<CW1, GNH, KC1, 4, true>), dim3(NX * GNH * KC1), dim3(256), 0, stream,
      bmp, Wt1, ss1, m1, pqk1, part1u, Zp1);
  hipLaunchKernelGGL(k_reduce1, dim3(GNH*GNP2*64/256), dim3(256), 0, stream,
      part1u, Zp1, h1t);
  hipLaunchKernelGGL(k_gemm_mfma, dim3((NRT+3)/4, 1), dim3(256), 0, stream,
      h1t, Wb2, as2f, at2f, Wt2, ss2, st2, 47);
  hipLaunchKernelGGL(k_stats, dim3(1), dim3(256), 0, stream, st2, m2, pqk2);
  hipLaunchKernelGGL((k_attn_t<CW2, 1, KC2, 3, false>), dim3(NX * KC2), dim3(256), 0, stream,
      bmp, Wt2, ss2, m2, pqk2, part2u, (float*)nullptr);
  hipLaunchKernelGGL(k_reduce2, dim3((GN*GNC+255)/256), dim3(256), 0, stream,
      part2u, out);
  hipLaunchKernelGGL(k_echo, dim3((GN*1500+255)/256), dim3(256), 0, stream, bmp, echo);
}

// Round 17
// 220.431 us; speedup vs baseline: 1.0390x; 1.0390x over previous
//
#include <hip/hip_runtime.h>
#include <hip/hip_bf16.h>
#include <stdint.h>

#define GN   6000
#define GNP2 3000          // row pairs
#define GFIN 512
#define GNH  8
#define GNC  40
#define WPR  192           // bitmask words per row (192*32 = 6144)
#define NT   192           // j-tiles per head (tail tiles zero-padded)
#define NRT  375           // row-tiles (16 rows), 375*16 = 6000 exact
#define PQS  6144
#define PQH  (PQS/2)       // pair-dwords per head
#define KC1  4             // attn1 K-chunks (48 w each)
#define CW1  48
#define KC2  32            // attn2 K-chunks (6 w each)
#define CW2  6

typedef __attribute__((ext_vector_type(8))) _Float16 half8v;  // 8 f16 (4 VGPRs)
typedef __attribute__((ext_vector_type(2))) _Float16 half2v;
typedef __attribute__((ext_vector_type(4))) float float4v;    // MFMA acc
typedef __attribute__((ext_vector_type(4))) float f32x4;

__device__ __forceinline__ uint32_t packh(float a, float b){
  half2v h = { (_Float16)a, (_Float16)b };
  return *(uint32_t*)&h;
}
__device__ __forceinline__ float h2lo(uint32_t u){ half2v h = *(half2v*)&u; return (float)h.x; }
__device__ __forceinline__ float h2hi(uint32_t u){ half2v h = *(half2v*)&u; return (float)h.y; }
// k-pair base for fragment dword t within k-group g (16x16x32 layout)
__device__ __forceinline__ int kmap(int g, int t){
  return (t < 2) ? 4*g + 2*t : 16 + 4*g + 2*(t - 2);
}
// permuted bit position: lane-group g's 8 bits contiguous at byte g
__device__ __forceinline__ int newpos(int gg, int c){
  return (gg < 4) ? 8*gg + c : 8*(gg-4) + 4 + c;
}
// masked weight: wv = m & max(p, ti*q), all packed f16 pairs
__device__ __forceinline__ uint32_t wvbuild(uint32_t ti2, uint32_t pq_q, uint32_t pq_p, uint32_t m){
  uint32_t prod, wvu;
  asm("v_pk_mul_f16 %0, %1, %2" : "=v"(prod) : "v"(ti2), "v"(pq_q));
  asm("v_pk_max_f16 %0, %1, %2" : "=v"(wvu) : "v"(pq_p), "v"(prod));
  return wvu & m;
}
// mask pair for bits (2t,2t+1) from u = b8 | (b8<<15): 2 ops per dword
__device__ __forceinline__ uint32_t mbuild_u(uint32_t u, int t, uint32_t s15){
  uint32_t pre = u << (15 - 2*t);
  uint32_t m;
  asm("v_pk_ashrrev_i16 %0, %1, %2" : "=v"(m) : "v"(s15), "v"(pre));
  return m;
}

// ---- prep: pad a2; zero pq arrays; zero Wt pad tiles (187..191) ----
__global__ void k_prep(const float* __restrict__ as2, const float* __restrict__ at2,
                       float* __restrict__ as2f, float* __restrict__ at2f,
                       uint32_t* __restrict__ Wt1, uint32_t* __restrict__ Wt2,
                       uint32_t* __restrict__ pqk1, uint32_t* __restrict__ pqk2){
  int i = blockIdx.x * 256 + threadIdx.x;
  if (i < 64) { as2f[i] = (i < GNC) ? as2[i] : 0.f; at2f[i] = (i < GNC) ? at2[i] : 0.f; }
  if (i < GNH*PQH*2) pqk1[i] = 0u;
  if (i < PQH*2) pqk2[i] = 0u;
  if (i < GNH*5*1024) {
    int h = i / 5120, rem = i - h * 5120;
    Wt1[((size_t)h*NT + 187)*1024 + rem] = 0u;
  }
  if (i < 5*1024) Wt2[(size_t)187*1024 + i] = 0u;
}

// ---- adjacency -> byte-permuted bitmask ----
__global__ void k_bitmask(const int* __restrict__ adj, uint32_t* __restrict__ bm){
  int idx = blockIdx.x * 256 + threadIdx.x;
  if (idx >= GN * WPR) return;
  int row = idx / WPR, w = idx - row * WPR;
  int j0 = w * 32;
  uint32_t bits = 0u;
  if (j0 < GN) {
    const int* a = adj + (size_t)row * GN + j0;
    int lim = GN - j0;
    if (lim >= 32) {
      const int4* a4 = (const int4*)a;
      #pragma unroll
      for (int gg = 0; gg < 8; ++gg) {
        int4 v = a4[gg];
        bits |= (v.x != 0 ? 1u : 0u) << newpos(gg, 0);
        bits |= (v.y != 0 ? 1u : 0u) << newpos(gg, 1);
        bits |= (v.z != 0 ? 1u : 0u) << newpos(gg, 2);
        bits |= (v.w != 0 ? 1u : 0u) << newpos(gg, 3);
      }
    } else {
      for (int b = 0; b < lim; ++b)
        bits |= (a[b] != 0 ? 1u : 0u) << newpos(b >> 2, b & 3);
    }
  }
  bm[idx] = bits;
}

// ---- x (f32) -> A-tiled f16 ----
__global__ void k_xtile(const float* __restrict__ x, uint32_t* __restrict__ xt){
  int idx = blockIdx.x * 256 + threadIdx.x;      // 375*16*256 exact
  int e = idx & 3, lane = (idx >> 2) & 63, kt = (idx >> 8) & 15, rt = idx >> 12;
  int g = lane >> 4, r = lane & 15;
  int k0 = kt*32 + kmap(g, e);
  const float* xp = x + (size_t)(rt*16 + r) * GFIN + k0;
  xt[idx] = packh(xp[0], xp[1]);
}

// ---- W1 -> B-tiled f16 ----
__global__ void k_wtile1(const float* __restrict__ W1, uint32_t* __restrict__ Wb1){
  int idx = blockIdx.x * 256 + threadIdx.x;      // 131072 exact
  int e = idx & 3, lane = (idx >> 2) & 63, n = (idx >> 8) & 3, kt = (idx >> 10) & 15, h = idx >> 14;
  int g = lane >> 4, col = n*16 + (lane & 15);
  int k0 = kt*32 + kmap(g, e);
  const float* wp = W1 + ((size_t)h*GFIN + k0) * 64 + col;
  Wb1[idx] = packh(wp[0], wp[64]);
}

// ---- W2 -> B-tiled f16, cols padded to 64 ----
__global__ void k_wtile2(const float* __restrict__ W2, uint32_t* __restrict__ Wb2){
  int idx = blockIdx.x * 256 + threadIdx.x;      // 16384 exact
  int e = idx & 3, lane = (idx >> 2) & 63, n = (idx >> 8) & 3, kt = idx >> 10;
  int g = lane >> 4, col = n*16 + (lane & 15);
  int k0 = kt*32 + kmap(g, e);
  float v0 = (col < GNC) ? W2[(size_t)k0*GNC + col]     : 0.f;
  float v1 = (col < GNC) ? W2[(size_t)(k0+1)*GNC + col] : 0.f;
  Wb2[idx] = packh(v0, v1);
}

// ---- MFMA GEMM (f16) -> Wh tiled f16 (optional ones-column) + scores ----
__global__ __launch_bounds__(256) void k_gemm_mfma(
    const uint32_t* __restrict__ At, const uint32_t* __restrict__ Bt,
    const float* __restrict__ asv, const float* __restrict__ atv,
    uint32_t* __restrict__ Wt, float* __restrict__ ss, float* __restrict__ st,
    int ones_col){
  int lane = threadIdx.x & 63;
  int wid  = threadIdx.x >> 6;
  int h  = blockIdx.y;
  int rt = blockIdx.x * 4 + wid;
  if (rt >= NRT) return;
  int g = lane >> 4, r = lane & 15;
  const uint32_t* Ab = At + (size_t)rt * 16 * 256 + lane * 4;
  const uint32_t* Bb = Bt + (size_t)h * 16 * 1024 + lane * 4;
  float4v acc[4];
  #pragma unroll
  for (int n = 0; n < 4; ++n) acc[n] = (float4v){0,0,0,0};
  for (int kt = 0; kt < 16; ++kt) {
    union { uint4 v; half8v hv; } A;
    A.v = *(const uint4*)(Ab + kt*256);
    #pragma unroll
    for (int n = 0; n < 4; ++n) {
      union { uint4 v; half8v hv; } B;
      B.v = *(const uint4*)(Bb + kt*1024 + n*256);
      acc[n] = __builtin_amdgcn_mfma_f32_16x16x32_f16(A.hv, B.hv, acc[n], 0, 0, 0);
    }
  }
  int row0 = rt * 16;
  int t01  = (row0 & 16) ? 2 : 0;
  uint32_t* dst = Wt + ((size_t)h*NT + (row0 >> 5)) * 1024 + lane*4 + t01;
  #pragma unroll
  for (int n = 0; n < 4; ++n) {
    uint2 val;
    if (n*16 + r == ones_col) val = make_uint2(0x3C003C00u, 0x3C003C00u);
    else val = make_uint2(packh(acc[n][0], acc[n][1]), packh(acc[n][2], acc[n][3]));
    *(uint2*)(dst + n*256) = val;
  }
  float av[4], tv[4];
  #pragma unroll
  for (int n = 0; n < 4; ++n) { av[n] = asv[h*64 + n*16 + r]; tv[n] = atv[h*64 + n*16 + r]; }
  #pragma unroll
  for (int reg = 0; reg < 4; ++reg) {
    float a = 0.f, b = 0.f;
    #pragma unroll
    for (int n = 0; n < 4; ++n) { a = fmaf(av[n], acc[n][reg], a); b = fmaf(tv[n], acc[n][reg], b); }
    #pragma unroll
    for (int d = 1; d < 16; d <<= 1) { a += __shfl_xor(a, d, 64); b += __shfl_xor(b, d, 64); }
    if (r == 0) {
      ss[(size_t)h*GN + row0 + 4*g + reg] = a;
      st[(size_t)h*GN + row0 + 4*g + reg] = b;
    }
  }
}

// ---- column stats: mh = max(s); interleaved pq pairs [p01,q01] per jp ----
__global__ void k_stats(const float* __restrict__ s_tgt, float* __restrict__ mh_out,
                        uint32_t* __restrict__ pqk){
  int h = blockIdx.x;
  __shared__ float red[256];
  float mx = -3.0e38f;
  for (int n = threadIdx.x; n < GN; n += 256) mx = fmaxf(mx, s_tgt[(size_t)h*GN + n]);
  red[threadIdx.x] = mx;
  __syncthreads();
  for (int d = 128; d > 0; d >>= 1) {
    if (threadIdx.x < d) red[threadIdx.x] = fmaxf(red[threadIdx.x], red[threadIdx.x + d]);
    __syncthreads();
  }
  float mh = red[0];
  if (threadIdx.x == 0) mh_out[h] = mh;
  for (int jp = threadIdx.x; jp < GNP2; jp += 256) {
    float s0 = s_tgt[(size_t)h*GN + 2*jp];
    float s1 = s_tgt[(size_t)h*GN + 2*jp + 1];
    pqk[((size_t)h*PQH + jp)*2]     = packh(expf(s0 - mh), expf(s1 - mh));
    pqk[((size_t)h*PQH + jp)*2 + 1] = packh(expf(0.2f*(s0 - mh)), expf(0.2f*(s1 - mh)));
  }
}

// ---- attention: 64 rows/wave, shared-u mask build (no setprio) ----
template<int CW, int NH, int KC, int NTILES, bool ONES>
__global__ __launch_bounds__(256) void k_attn_t(
    const uint32_t* __restrict__ bmp, const uint32_t* __restrict__ Wt,
    const float* __restrict__ ss, const float* __restrict__ mh_arr,
    const uint32_t* __restrict__ pqk,
    uint32_t* __restrict__ part, float* __restrict__ Zp){
  int lane = threadIdx.x & 63;
  int wid  = threadIdx.x >> 6;
  constexpr int NB = NH * KC;        // NB % 8 == 0 -> (h,ch) pinned to one XCD
  int combo = blockIdx.x % NB;
  int x     = blockIdx.x / NB;
  int h  = combo / KC;
  int ch = combo % KC;
  int base = x * 256 + wid * 64;
  int g = lane >> 4, r = lane & 15;
  uint32_t s15 = 0x000F000Fu;
  float mh = mh_arr[h];
  const uint32_t* bmr[4];
  uint32_t ti2u[4];
  #pragma unroll
  for (int tt = 0; tt < 4; ++tt) {
    int row = base + 16*tt + r;
    int rc = row < GN-1 ? row : GN-1;
    float ti = expf(-0.8f * (ss[(size_t)h*GN + rc] + mh));
    ti2u[tt] = packh(ti, ti);
    bmr[tt] = bmp + (size_t)rc * WPR;
  }
  const uint32_t* pqh = pqk + (size_t)h * PQH * 2;
  const uint32_t* wt  = Wt + (size_t)h * NT * 1024;
  float4v acc[4][NTILES];
  float4v az[4];
  #pragma unroll
  for (int tt = 0; tt < 4; ++tt) {
    #pragma unroll
    for (int n = 0; n < NTILES; ++n) acc[tt][n] = (float4v){0,0,0,0};
    if (ONES) az[tt] = (float4v){0,0,0,0};
  }
  union { uint32_t u4[4]; half8v hv; } Bones;
  if (ONES) {
    uint32_t ov = (r == 0) ? 0x3C003C00u : 0u;
    Bones.u4[0] = ov; Bones.u4[1] = ov; Bones.u4[2] = ov; Bones.u4[3] = ov;
  }
  const int w0 = ch * CW;
  for (int wp = 0; wp < CW/2; ++wp) {
    uint2 bw2[4];
    #pragma unroll
    for (int tt = 0; tt < 4; ++tt) bw2[tt] = *(const uint2*)(bmr[tt] + w0 + 2*wp);
    #pragma unroll
    for (int e = 0; e < 2; ++e) {
      int w = w0 + 2*wp + e;
      int jp = w * 16;
      uint4 pqA = *(const uint4*)(pqh + (size_t)(jp + 2*g) * 2);      // p01 q01 p23 q23
      uint4 pqB = *(const uint4*)(pqh + (size_t)(jp + 8 + 2*g) * 2);
      const uint32_t* tb = wt + (size_t)w * 1024 + lane * 4;
      union { uint4 v; half8v hv; } B[NTILES];
      #pragma unroll
      for (int n = 0; n < NTILES; ++n) B[n].v = *(const uint4*)(tb + n*256);
      #pragma unroll
      for (int tt = 0; tt < 4; ++tt) {
        uint32_t b8 = ((e ? bw2[tt].y : bw2[tt].x) >> (8*g)) & 0xFFu;
        uint32_t u = b8 | (b8 << 15);       // shared mask base (2 ops / 4 dwords)
        union { uint32_t u4[4]; half8v hv; } A;
        A.u4[0] = wvbuild(ti2u[tt], pqA.y, pqA.x, mbuild_u(u, 0, s15));
        A.u4[1] = wvbuild(ti2u[tt], pqA.w, pqA.z, mbuild_u(u, 1, s15));
        A.u4[2] = wvbuild(ti2u[tt], pqB.y, pqB.x, mbuild_u(u, 2, s15));
        A.u4[3] = wvbuild(ti2u[tt], pqB.w, pqB.z, mbuild_u(u, 3, s15));
        #pragma unroll
        for (int n = 0; n < NTILES; ++n)
          acc[tt][n] = __builtin_amdgcn_mfma_f32_16x16x32_f16(A.hv, B[n].hv, acc[tt][n], 0, 0, 0);
        if (ONES)
          az[tt] = __builtin_amdgcn_mfma_f32_16x16x32_f16(A.hv, Bones.hv, az[tt], 0, 0, 0);
      }
    }
  }
  constexpr int PST = NTILES * 16;
  size_t pb = ((size_t)(ch * NH + h)) * GNP2;
  #pragma unroll
  for (int tt = 0; tt < 4; ++tt) {
    int row0t = base + 16*tt;
    if (row0t >= GN) break;                 // tiles are 16-aligned: all-or-nothing
    int pra = (row0t >> 1) + 2*g;
    #pragma unroll
    for (int n = 0; n < NTILES; ++n) {
      part[(pb + pra    )*PST + n*16 + r] = packh(acc[tt][n][0], acc[tt][n][1]);
      part[(pb + pra + 1)*PST + n*16 + r] = packh(acc[tt][n][2], acc[tt][n][3]);
    }
    if (ONES && r == 0) {
      size_t zb = ((size_t)(ch * NH + h)) * GN;
      #pragma unroll
      for (int reg = 0; reg < 4; ++reg) Zp[zb + row0t + 4*g + reg] = az[tt][reg];
    }
  }
}

// ---- combine L1 chunks (f16 pairs): normalize, ELU, h1 A-tile f16 write ----
__global__ void k_reduce1(const uint32_t* __restrict__ part1, const float* __restrict__ Zp1,
                          uint32_t* __restrict__ h1t){
  int idx = blockIdx.x * 256 + threadIdx.x;
  if (idx >= GNH*GNP2*64) return;
  int o = idx & 63;
  int t = idx >> 6;
  int pr = t % GNP2;
  int h = t / GNP2;
  float s0 = 0.f, s1 = 0.f, z0 = 0.f, z1 = 0.f;
  #pragma unroll
  for (int c = 0; c < KC1; ++c) {
    uint32_t dw = part1[(((size_t)(c*GNH + h))*GNP2 + pr)*64 + o];
    s0 += h2lo(dw);
    s1 += h2hi(dw);
    size_t zb = ((size_t)(c*GNH + h))*GN + 2*pr;
    z0 += Zp1[zb]; z1 += Zp1[zb + 1];
  }
  float v0 = s0 / z0, v1 = s1 / z1;
  v0 = v0 > 0.f ? v0 : (expf(v0) - 1.f);
  v1 = v1 > 0.f ? v1 : (expf(v1) - 1.f);
  int n0 = 2*pr;
  int rt = n0 >> 4, rr = n0 & 15;
  int k = h*64 + o;
  int kt = k >> 5, joff = k & 31;
  int g, tt, b;
  if (joff < 16) { g = joff >> 2; tt = (joff & 3) >> 1;        b = joff & 1; }
  else { int jo = joff - 16; g = jo >> 2; tt = 2 + ((jo & 3) >> 1); b = jo & 1; }
  size_t dw0 = ((size_t)(rt*16 + kt))*256 + (g*16 + rr)*4 + tt;
  _Float16* hp = (_Float16*)h1t;
  hp[dw0*2 + b]     = (_Float16)v0;
  hp[(dw0+4)*2 + b] = (_Float16)v1;
}

// ---- combine L2 chunks: normalize (Z = col 47), f32 logits ----
__global__ void k_reduce2(const uint32_t* __restrict__ part2, float* __restrict__ out){
  int idx = blockIdx.x * 256 + threadIdx.x;
  if (idx >= GN * GNC) return;
  int n = idx / GNC, c = idx - n * GNC;
  int pr = n >> 1, half = n & 1;
  float s = 0.f, z = 0.f;
  #pragma unroll 8
  for (int ch = 0; ch < KC2; ++ch) {
    const uint32_t* row = part2 + ((size_t)ch * GNP2 + pr) * 48;
    uint32_t dS = row[c], dZ = row[47];
    s += half ? h2hi(dS) : h2lo(dS);
    z += half ? h2hi(dZ) : h2lo(dZ);
  }
  out[idx] = s / z;
}

// ---- adjacency echo (f32): one float4 per thread, globally contiguous stores ----
__global__ void k_echo(const uint32_t* __restrict__ bm, float* __restrict__ echo){
  int idx = blockIdx.x * 256 + threadIdx.x;     // GN*1500 = 9,000,000 exact chunks
  if (idx >= GN * 1500) return;
  int row = idx / 1500, c = idx - row * 1500;
  uint32_t bits = bm[(size_t)row * WPR + (c >> 3)];
  int gg = c & 7;
  f32x4 f;
  f.x = ((bits >> newpos(gg,0)) & 1u) ? 1.f : 0.f;
  f.y = ((bits >> newpos(gg,1)) & 1u) ? 1.f : 0.f;
  f.z = ((bits >> newpos(gg,2)) & 1u) ? 1.f : 0.f;
  f.w = ((bits >> newpos(gg,3)) & 1u) ? 1.f : 0.f;
  *(f32x4*)(echo + (size_t)idx * 4) = f;
}

extern "C" void kernel_launch(void* const* d_in, const int* in_sizes, int n_in,
                              void* d_out, int out_size, void* d_ws, size_t ws_size,
                              hipStream_t stream){
  const float* x   = (const float*)d_in[0];
  const int*   adj = (const int*)d_in[1];
  const float* W1  = (const float*)d_in[2];
  const float* as1 = (const float*)d_in[3];
  const float* at1 = (const float*)d_in[4];
  const float* W2  = (const float*)d_in[5];
  const float* as2 = (const float*)d_in[6];
  const float* at2 = (const float*)d_in[7];
  float* out  = (float*)d_out;                    // f32 logits [6000,40]
  float* echo = out + (size_t)GN * GNC;           // f32 adj echo [6000,6000]
  (void)in_sizes; (void)n_in; (void)out_size; (void)ws_size;

  // scratch in echo region (dead before k_echo overwrites)
  uint32_t* part1u = (uint32_t*)echo;                              // 6.144M dw
  float*    Zp1    = (float*)(part1u + (size_t)KC1*GNH*GNP2*64);   // 192K f32
  uint32_t* part2u = (uint32_t*)(Zp1 + (size_t)KC1*GNH*GN);        // 4.608M dw
  uint32_t* h1t    = part2u + (size_t)KC2*GNP2*48;                 // 1.536M dw
  uint32_t* xt     = h1t + (size_t)NRT*16*256;                     // 1.536M dw

  char* wsb = (char*)d_ws;
  size_t off = 0;
  auto alloc = [&](size_t bytes) -> void* {
    void* r = wsb + off;
    off = (off + bytes + 255) & ~(size_t)255;
    return r;
  };
  uint32_t* bmp  = (uint32_t*)alloc((size_t)GN * WPR * 4);
  uint32_t* Wt1  = (uint32_t*)alloc((size_t)GNH * NT * 1024 * 4);
  uint32_t* Wt2  = (uint32_t*)alloc((size_t)NT * 1024 * 4);
  uint32_t* Wb1  = (uint32_t*)alloc((size_t)GNH * 16 * 1024 * 4);
  uint32_t* Wb2  = (uint32_t*)alloc((size_t)16 * 1024 * 4);
  float*    as2f = (float*)alloc(64 * 4);
  float*    at2f = (float*)alloc(64 * 4);
  float*    ss1  = (float*)alloc((size_t)GNH * GN * 4);
  float*    st1  = (float*)alloc((size_t)GNH * GN * 4);
  uint32_t* pqk1 = (uint32_t*)alloc((size_t)GNH * PQH * 2 * 4);
  float*    m1   = (float*)alloc(64);
  float*    ss2  = (float*)alloc((size_t)GN * 4);
  float*    st2  = (float*)alloc((size_t)GN * 4);
  uint32_t* pqk2 = (uint32_t*)alloc((size_t)PQH * 2 * 4);
  float*    m2   = (float*)alloc(64);

  const int NX = (GN + 255) / 256;    // 24 row-blocks (attn, 256 rows each)

  hipLaunchKernelGGL(k_prep, dim3(192), dim3(256), 0, stream,
      as2, at2, as2f, at2f, Wt1, Wt2, pqk1, pqk2);
  hipLaunchKernelGGL(k_bitmask, dim3(GN*WPR/256), dim3(256), 0, stream, adj, bmp);
  hipLaunchKernelGGL(k_xtile, dim3(NRT*16*256/256), dim3(256), 0, stream, x, xt);
  hipLaunchKernelGGL(k_wtile1, dim3(512), dim3(256), 0, stream, W1, Wb1);
  hipLaunchKernelGGL(k_wtile2, dim3(64), dim3(256), 0, stream, W2, Wb2);
  hipLaunchKernelGGL(k_gemm_mfma, dim3((NRT+3)/4, GNH), dim3(256), 0, stream,
      xt, Wb1, as1, at1, Wt1, ss1, st1, -1);
  hipLaunchKernelGGL(k_stats, dim3(GNH), dim3(256), 0, stream, st1, m1, pqk1);
  hipLaunchKernelGGL((k_attn_t<CW1, GNH, KC1, 4, true>), dim3(NX * GNH * KC1), dim3(256), 0, stream,
      bmp, Wt1, ss1, m1, pqk1, part1u, Zp1);
  hipLaunchKernelGGL(k_reduce1, dim3(GNH*GNP2*64/256), dim3(256), 0, stream,
      part1u, Zp1, h1t);
  hipLaunchKernelGGL(k_gemm_mfma, dim3((NRT+3)/4, 1), dim3(256), 0, stream,
      h1t, Wb2, as2f, at2f, Wt2, ss2, st2, 47);
  hipLaunchKernelGGL(k_stats, dim3(1), dim3(256), 0, stream, st2, m2, pqk2);
  hipLaunchKernelGGL((k_attn_t<CW2, 1, KC2, 3, false>), dim3(NX * KC2), dim3(256), 0, stream,
      bmp, Wt2, ss2, m2, pqk2, part2u, (float*)nullptr);
  hipLaunchKernelGGL(k_reduce2, dim3((GN*GNC+255)/256), dim3(256), 0, stream,
      part2u, out);
  hipLaunchKernelGGL(k_echo, dim3((GN*1500+255)/256), dim3(256), 0, stream, bmp, echo);
}